// Round 1
// baseline (247.177 us; speedup 1.0000x reference)
//
#include <hip/hip_runtime.h>
#include <cstdint>
#include <cstddef>

// ---------------------------------------------------------------------------
// Fused MHA forward: out = softmax((xWq^T+bq)(xWk^T+bk)^T / sqrt(Hd)) (xWv^T+bv)
// B=8, S=1024, D=1024, H=16, Hd=64.  bf16 MFMA pipeline, fp32 accum/output.
// ---------------------------------------------------------------------------

typedef __attribute__((ext_vector_type(8))) short bf16x8;
typedef __attribute__((ext_vector_type(4))) float f32x4;

typedef const __attribute__((address_space(1))) void* gptr_t;
typedef __attribute__((address_space(3))) void* lptr_t;

#define LOG2E 1.44269504088896340736f

__device__ __forceinline__ unsigned short f2bf(float f) {
  unsigned int u = __float_as_uint(f);
  u += 0x7fffu + ((u >> 16) & 1u);       // round-to-nearest-even
  return (unsigned short)(u >> 16);
}
__device__ __forceinline__ float bf2f(unsigned short b) {
  return __uint_as_float(((unsigned int)b) << 16);
}

// ---------------------------------------------------------------------------
// fp32 -> bf16 conversion, 4 elems/thread
// ---------------------------------------------------------------------------
__global__ void cvt_f32_bf16(const float* __restrict__ src,
                             unsigned short* __restrict__ dst, int n4) {
  int i = blockIdx.x * blockDim.x + threadIdx.x;
  if (i >= n4) return;
  float4 v = reinterpret_cast<const float4*>(src)[i];
  ushort4 o;
  o.x = f2bf(v.x); o.y = f2bf(v.y); o.z = f2bf(v.z); o.w = f2bf(v.w);
  reinterpret_cast<ushort4*>(dst)[i] = o;
}

// ---------------------------------------------------------------------------
// QKV GEMM: Y[8192][3072] = Xb[8192][1024] @ Wb[3072][1024]^T  (+bias)
// 128x128 tile, BK=32, 4 waves (2x2), 16x16x32 bf16 MFMA, global_load_lds.
// Epilogue scatters into Q/K/V [B][H][S][Hd] bf16.
// ---------------------------------------------------------------------------
__global__ __launch_bounds__(256) void qkv_gemm(
    const unsigned short* __restrict__ Xb, const unsigned short* __restrict__ Wb,
    const float* __restrict__ bq, const float* __restrict__ bk,
    const float* __restrict__ bv,
    unsigned short* __restrict__ Qo, unsigned short* __restrict__ Ko,
    unsigned short* __restrict__ Vo) {
  __shared__ unsigned short As[128 * 32];   // [row][k] 64B rows
  __shared__ unsigned short Bs[128 * 32];

  const int tid = threadIdx.x;
  const int lane = tid & 63;
  const int w = tid >> 6;
  const int wr = w >> 1, wc = w & 1;
  const int bm = blockIdx.x & 63;   // 64 M-blocks
  const int bn = blockIdx.x >> 6;   // 24 N-blocks

  const f32x4 vzero = {0.f, 0.f, 0.f, 0.f};
  f32x4 acc[4][4];
#pragma unroll
  for (int m = 0; m < 4; ++m)
#pragma unroll
    for (int n = 0; n < 4; ++n) acc[m][n] = vzero;

  // staging: per wave 2 chunks of 1KB per matrix; chunk = 16 rows x 64B
  const int c0 = w * 2, c1 = w * 2 + 1;
  const int srow0 = c0 * 16 + (lane >> 2);
  const int srow1 = c1 * 16 + (lane >> 2);
  const int scol = (lane & 3) * 8;
  const unsigned short* gA0 = Xb + (size_t)(bm * 128 + srow0) * 1024 + scol;
  const unsigned short* gA1 = Xb + (size_t)(bm * 128 + srow1) * 1024 + scol;
  const unsigned short* gB0 = Wb + (size_t)(bn * 128 + srow0) * 1024 + scol;
  const unsigned short* gB1 = Wb + (size_t)(bn * 128 + srow1) * 1024 + scol;
  char* lA0 = (char*)As + c0 * 1024;
  char* lA1 = (char*)As + c1 * 1024;
  char* lB0 = (char*)Bs + c0 * 1024;
  char* lB1 = (char*)Bs + c1 * 1024;

  const int aoff = (wr * 64 + (lane & 15)) * 64 + (lane >> 4) * 16;
  const int boff = (wc * 64 + (lane & 15)) * 64 + (lane >> 4) * 16;

  for (int kt = 0; kt < 32; ++kt) {
    const int k0 = kt * 32;
    __builtin_amdgcn_global_load_lds((gptr_t)(gA0 + k0), (lptr_t)lA0, 16, 0, 0);
    __builtin_amdgcn_global_load_lds((gptr_t)(gA1 + k0), (lptr_t)lA1, 16, 0, 0);
    __builtin_amdgcn_global_load_lds((gptr_t)(gB0 + k0), (lptr_t)lB0, 16, 0, 0);
    __builtin_amdgcn_global_load_lds((gptr_t)(gB1 + k0), (lptr_t)lB1, 16, 0, 0);
    __syncthreads();

    bf16x8 a[4], b[4];
#pragma unroll
    for (int m = 0; m < 4; ++m)
      a[m] = *reinterpret_cast<const bf16x8*>((const char*)As + aoff + m * 16 * 64);
#pragma unroll
    for (int n = 0; n < 4; ++n)
      b[n] = *reinterpret_cast<const bf16x8*>((const char*)Bs + boff + n * 16 * 64);
#pragma unroll
    for (int m = 0; m < 4; ++m)
#pragma unroll
      for (int n = 0; n < 4; ++n)
        acc[m][n] = __builtin_amdgcn_mfma_f32_16x16x32_bf16(a[m], b[n], acc[m][n], 0, 0, 0);
    __syncthreads();
  }

  // epilogue: bias + scatter to [B][H][S][Hd] bf16 (t uniform per block: 128 | 1024)
  const int t = bn >> 3;   // 0:Q 1:K 2:V
  const float* bias = (t == 0) ? bq : (t == 1) ? bk : bv;
  unsigned short* dst = (t == 0) ? Qo : (t == 1) ? Ko : Vo;
#pragma unroll
  for (int n = 0; n < 4; ++n) {
    const int gn = bn * 128 + wc * 64 + n * 16 + (lane & 15);
    const int d = gn & 1023;
    const int h = d >> 6, hd = d & 63;
    const float bias_v = bias[d];
#pragma unroll
    for (int m = 0; m < 4; ++m) {
      const int gm0 = bm * 128 + wr * 64 + m * 16 + ((lane >> 4) << 2);
      const int bb = gm0 >> 10;
      const int s0 = gm0 & 1023;
#pragma unroll
      for (int r = 0; r < 4; ++r) {
        dst[(((size_t)bb * 16 + h) * 1024 + (size_t)(s0 + r)) * 64 + hd] =
            f2bf(acc[m][n][r] + bias_v);
      }
    }
  }
}

// ---------------------------------------------------------------------------
// Flash attention: per block one (head, 64-row Q tile); 4 waves x 16 q-rows.
// K tiles of 64 rows, online softmax, PV accumulate, fp32 out [B][S][D].
// LDS rows are 128B -> XOR swizzle byte ^= (row&7)<<4 to kill bank conflicts.
// ---------------------------------------------------------------------------
__global__ __launch_bounds__(256) void attn64(
    const unsigned short* __restrict__ Q, const unsigned short* __restrict__ K,
    const unsigned short* __restrict__ V, float* __restrict__ out) {
  __shared__ unsigned short Qs[64 * 64];
  __shared__ unsigned short Ks[64 * 64];
  __shared__ unsigned short Vt[64 * 64];      // V transposed: [d][kk]
  __shared__ unsigned short Pl[4][16 * 64];   // per-wave P tile

  const int tid = threadIdx.x;
  const int lane = tid & 63;
  const int w = tid >> 6;
  const int head = blockIdx.x & 127;   // b*16+h ; qt-major so head -> fixed XCD
  const int qt = blockIdx.x >> 7;

  const unsigned short* Qh = Q + (size_t)head * 65536;
  const unsigned short* Kh = K + (size_t)head * 65536;
  const unsigned short* Vh = V + (size_t)head * 65536;

  // stage Q tile [64][64] swizzled
  for (int c = tid; c < 512; c += 256) {
    const int row = c >> 3, slot = c & 7;
    int4 v = *reinterpret_cast<const int4*>(Qh + (size_t)(qt * 64 + row) * 64 + slot * 8);
    *reinterpret_cast<int4*>((char*)Qs + row * 128 + ((slot ^ (row & 7)) << 4)) = v;
  }
  __syncthreads();

  // Q fragments held in registers for the whole kernel
  bf16x8 qf[2];
  {
    const int row = w * 16 + (lane & 15);
    const int sw = (row & 7) << 4;
#pragma unroll
    for (int ks = 0; ks < 2; ++ks)
      qf[ks] = *reinterpret_cast<const bf16x8*>(
          (const char*)Qs + row * 128 + ((ks * 64 + (lane >> 4) * 16) ^ sw));
  }

  float m_[4], l_[4];
#pragma unroll
  for (int r = 0; r < 4; ++r) { m_[r] = -1e30f; l_[r] = 0.f; }
  const f32x4 vzero = {0.f, 0.f, 0.f, 0.f};
  f32x4 acc[4];
#pragma unroll
  for (int db = 0; db < 4; ++db) acc[db] = vzero;

  for (int kt = 0; kt < 16; ++kt) {
    // stage K tile [64][64] swizzled (row-major)
    for (int c = tid; c < 512; c += 256) {
      const int row = c >> 3, slot = c & 7;
      int4 v = *reinterpret_cast<const int4*>(Kh + (size_t)(kt * 64 + row) * 64 + slot * 8);
      *reinterpret_cast<int4*>((char*)Ks + row * 128 + ((slot ^ (row & 7)) << 4)) = v;
    }
    // stage V transposed: Vt[d][kk] (2B scatter writes, swizzled)
    for (int c = tid; c < 512; c += 256) {
      const int kk = c >> 3, d0 = (c & 7) * 8;
      bf16x8 v = *reinterpret_cast<const bf16x8*>(Vh + (size_t)(kt * 64 + kk) * 64 + d0);
#pragma unroll
      for (int j = 0; j < 8; ++j) {
        const int rr = d0 + j;
        *(unsigned short*)((char*)Vt + ((rr * 128 + kk * 2) ^ ((rr & 7) << 4))) =
            (unsigned short)v[j];
      }
    }
    __syncthreads();

    // S = Q K^T  (per wave: 16 q-rows x 64 kk)
    f32x4 s[4];
#pragma unroll
    for (int cb = 0; cb < 4; ++cb) s[cb] = vzero;
#pragma unroll
    for (int ks = 0; ks < 2; ++ks) {
#pragma unroll
      for (int cb = 0; cb < 4; ++cb) {
        const int row = cb * 16 + (lane & 15);
        const int sw = (row & 7) << 4;
        bf16x8 kf = *reinterpret_cast<const bf16x8*>(
            (const char*)Ks + row * 128 + ((ks * 64 + (lane >> 4) * 16) ^ sw));
        s[cb] = __builtin_amdgcn_mfma_f32_16x16x32_bf16(qf[ks], kf, s[cb], 0, 0, 0);
      }
    }
#pragma unroll
    for (int cb = 0; cb < 4; ++cb) s[cb] *= 0.125f;   // 1/sqrt(64)

    // online softmax: lane's 4 rows are (lane>>4)*4 + r; cols spread over
    // 16-lane groups x 4 col-blocks -> butterfly over xor {1,2,4,8}
    float al[4];
    unsigned short pbv[4][4];
#pragma unroll
    for (int r = 0; r < 4; ++r) {
      float tm = fmaxf(fmaxf(s[0][r], s[1][r]), fmaxf(s[2][r], s[3][r]));
#pragma unroll
      for (int off = 1; off <= 8; off <<= 1) tm = fmaxf(tm, __shfl_xor(tm, off));
      const float mn = fmaxf(m_[r], tm);
      al[r] = exp2f((m_[r] - mn) * LOG2E);
      m_[r] = mn;
      float ts = 0.f;
#pragma unroll
      for (int cb = 0; cb < 4; ++cb) {
        const float p = exp2f((s[cb][r] - mn) * LOG2E);
        const unsigned short pb = f2bf(p);
        pbv[cb][r] = pb;
        ts += bf2f(pb);   // sum the rounded values -> consistent numerator/denominator
      }
#pragma unroll
      for (int off = 1; off <= 8; off <<= 1) ts += __shfl_xor(ts, off);
      l_[r] = l_[r] * al[r] + ts;
    }
#pragma unroll
    for (int db = 0; db < 4; ++db) {
      f32x4 a4 = acc[db];
      a4[0] *= al[0]; a4[1] *= al[1]; a4[2] *= al[2]; a4[3] *= al[3];
      acc[db] = a4;
    }

    // P (D-layout regs) -> wave-private LDS -> A-fragment layout
    {
      const int g4 = (lane >> 4) * 4;
#pragma unroll
      for (int cb = 0; cb < 4; ++cb)
#pragma unroll
        for (int r = 0; r < 4; ++r) {
          const int prow = g4 + r;
          const int pcol = cb * 16 + (lane & 15);
          *(unsigned short*)((char*)Pl + w * 2048 +
                             ((prow * 128 + pcol * 2) ^ ((prow & 7) << 4))) = pbv[cb][r];
        }
    }
    bf16x8 pf[2];
    {
      const int prow = lane & 15;
      const int sw = (prow & 7) << 4;
#pragma unroll
      for (int ks = 0; ks < 2; ++ks)
        pf[ks] = *reinterpret_cast<const bf16x8*>(
            (const char*)Pl + w * 2048 + prow * 128 + ((ks * 64 + (lane >> 4) * 16) ^ sw));
    }

    // ctx += P @ V   (B operand = Vt rows)
#pragma unroll
    for (int db = 0; db < 4; ++db) {
      const int vrow = db * 16 + (lane & 15);
      const int sw = (vrow & 7) << 4;
#pragma unroll
      for (int ks = 0; ks < 2; ++ks) {
        bf16x8 vf = *reinterpret_cast<const bf16x8*>(
            (const char*)Vt + vrow * 128 + ((ks * 64 + (lane >> 4) * 16) ^ sw));
        acc[db] = __builtin_amdgcn_mfma_f32_16x16x32_bf16(pf[ks], vf, acc[db], 0, 0, 0);
      }
    }
    __syncthreads();
  }

  // epilogue: out[b][s][h*64 + d] fp32
  const int bb = head >> 4, hh = head & 15;
  const int g4 = (lane >> 4) << 2;
#pragma unroll
  for (int db = 0; db < 4; ++db)
#pragma unroll
    for (int r = 0; r < 4; ++r) {
      const int srow = qt * 64 + w * 16 + g4 + r;
      out[((size_t)bb * 1024 + srow) * 1024 + hh * 64 + db * 16 + (lane & 15)] =
          acc[db][r] / l_[r];
    }
}

// ---------------------------------------------------------------------------
extern "C" void kernel_launch(void* const* d_in, const int* in_sizes, int n_in,
                              void* d_out, int out_size, void* d_ws, size_t ws_size,
                              hipStream_t stream) {
  const float* x  = (const float*)d_in[0];
  const float* Wq = (const float*)d_in[1];
  const float* Wk = (const float*)d_in[2];
  const float* Wv = (const float*)d_in[3];
  const float* bq = (const float*)d_in[4];
  const float* bk = (const float*)d_in[5];
  const float* bv = (const float*)d_in[6];
  float* out = (float*)d_out;

  char* ws = (char*)d_ws;
  unsigned short* Xb = (unsigned short*)(ws);                               // 16 MB
  unsigned short* Wb = (unsigned short*)(ws + (size_t)16 * 1024 * 1024);    //  6 MB
  unsigned short* Qb = (unsigned short*)(ws + (size_t)22 * 1024 * 1024);    // 16 MB
  unsigned short* Kb = Qb + (size_t)8 * 1024 * 1024;                        // 16 MB
  unsigned short* Vb = Kb + (size_t)8 * 1024 * 1024;                        // 16 MB

  // fp32 -> bf16
  cvt_f32_bf16<<<8192, 256, 0, stream>>>(x, Xb, 2097152);
  cvt_f32_bf16<<<1024, 256, 0, stream>>>(Wq, Wb, 262144);
  cvt_f32_bf16<<<1024, 256, 0, stream>>>(Wk, Wb + 1048576, 262144);
  cvt_f32_bf16<<<1024, 256, 0, stream>>>(Wv, Wb + 2097152, 262144);

  // fused QKV projection (M=8192, N=3072, K=1024)
  qkv_gemm<<<1536, 256, 0, stream>>>(Xb, Wb, bq, bk, bv, Qb, Kb, Vb);

  // flash attention: 16 q-tiles x 128 heads (qt-major -> head pinned to XCD)
  attn64<<<2048, 256, 0, stream>>>(Qb, Kb, Vb, out);
}

// Round 3
// 194.139 us; speedup vs baseline: 1.2732x; 1.2732x over previous
//
#include <hip/hip_runtime.h>
#include <cstdint>
#include <cstddef>

// ---------------------------------------------------------------------------
// Fused MHA forward: out = softmax((xWq^T+bq)(xWk^T+bk)^T / sqrt(Hd)) (xWv^T+bv)
// B=8, S=1024, D=1024, H=16, Hd=64.  bf16 MFMA pipeline, fp32 accum/output.
// Round 3: swapped-operand 32x32x16 attention, conservative P-path:
//   P -> bf16 via verified f2bf (RNE), P routed through wave-private LDS
//   (u32 writes, XOR swizzle) instead of cvt_pk asm + shfl exchange.
//   l_ sums ROUNDED p for exact numerator/denominator consistency.
// ---------------------------------------------------------------------------

typedef __attribute__((ext_vector_type(8))) short bf16x8;
typedef __attribute__((ext_vector_type(4))) float f32x4;
typedef __attribute__((ext_vector_type(16))) float f32x16;

typedef const __attribute__((address_space(1))) void* gptr_t;
typedef __attribute__((address_space(3))) void* lptr_t;

#define LOG2E 1.44269504088896340736f

__device__ __forceinline__ unsigned short f2bf(float f) {
  unsigned int u = __float_as_uint(f);
  u += 0x7fffu + ((u >> 16) & 1u);       // round-to-nearest-even
  return (unsigned short)(u >> 16);
}
__device__ __forceinline__ float bf2f(unsigned short b) {
  return __uint_as_float(((unsigned int)b) << 16);
}

// ---------------------------------------------------------------------------
// fp32 -> bf16 conversion, 4 elems/thread
// ---------------------------------------------------------------------------
__global__ void cvt_f32_bf16(const float* __restrict__ src,
                             unsigned short* __restrict__ dst, int n4) {
  int i = blockIdx.x * blockDim.x + threadIdx.x;
  if (i >= n4) return;
  float4 v = reinterpret_cast<const float4*>(src)[i];
  ushort4 o;
  o.x = f2bf(v.x); o.y = f2bf(v.y); o.z = f2bf(v.z); o.w = f2bf(v.w);
  reinterpret_cast<ushort4*>(dst)[i] = o;
}

// ---------------------------------------------------------------------------
// QKV GEMM: Y[8192][3072] = Xb[8192][1024] @ Wb[3072][1024]^T  (+bias)
// 128x128 tile, BK=32, 4 waves (2x2), 16x16x32 bf16 MFMA, global_load_lds.
// Epilogue: Q scaled by 0.125 (exact), Q/K -> [B][H][S][Hd], V -> [B][H][Hd][S].
// ---------------------------------------------------------------------------
__global__ __launch_bounds__(256) void qkv_gemm(
    const unsigned short* __restrict__ Xb, const unsigned short* __restrict__ Wb,
    const float* __restrict__ bq, const float* __restrict__ bk,
    const float* __restrict__ bv,
    unsigned short* __restrict__ Qo, unsigned short* __restrict__ Ko,
    unsigned short* __restrict__ Vo) {
  __shared__ unsigned short As[128 * 32];   // [row][k] 64B rows
  __shared__ unsigned short Bs[128 * 32];

  const int tid = threadIdx.x;
  const int lane = tid & 63;
  const int w = tid >> 6;
  const int wr = w >> 1, wc = w & 1;
  const int bm = blockIdx.x & 63;   // 64 M-blocks
  const int bn = blockIdx.x >> 6;   // 24 N-blocks

  const f32x4 vzero = {0.f, 0.f, 0.f, 0.f};
  f32x4 acc[4][4];
#pragma unroll
  for (int m = 0; m < 4; ++m)
#pragma unroll
    for (int n = 0; n < 4; ++n) acc[m][n] = vzero;

  // staging: per wave 2 chunks of 1KB per matrix; chunk = 16 rows x 64B
  const int c0 = w * 2, c1 = w * 2 + 1;
  const int srow0 = c0 * 16 + (lane >> 2);
  const int srow1 = c1 * 16 + (lane >> 2);
  const int scol = (lane & 3) * 8;
  const unsigned short* gA0 = Xb + (size_t)(bm * 128 + srow0) * 1024 + scol;
  const unsigned short* gA1 = Xb + (size_t)(bm * 128 + srow1) * 1024 + scol;
  const unsigned short* gB0 = Wb + (size_t)(bn * 128 + srow0) * 1024 + scol;
  const unsigned short* gB1 = Wb + (size_t)(bn * 128 + srow1) * 1024 + scol;
  char* lA0 = (char*)As + c0 * 1024;
  char* lA1 = (char*)As + c1 * 1024;
  char* lB0 = (char*)Bs + c0 * 1024;
  char* lB1 = (char*)Bs + c1 * 1024;

  const int aoff = (wr * 64 + (lane & 15)) * 64 + (lane >> 4) * 16;
  const int boff = (wc * 64 + (lane & 15)) * 64 + (lane >> 4) * 16;

  for (int kt = 0; kt < 32; ++kt) {
    const int k0 = kt * 32;
    __builtin_amdgcn_global_load_lds((gptr_t)(gA0 + k0), (lptr_t)lA0, 16, 0, 0);
    __builtin_amdgcn_global_load_lds((gptr_t)(gA1 + k0), (lptr_t)lA1, 16, 0, 0);
    __builtin_amdgcn_global_load_lds((gptr_t)(gB0 + k0), (lptr_t)lB0, 16, 0, 0);
    __builtin_amdgcn_global_load_lds((gptr_t)(gB1 + k0), (lptr_t)lB1, 16, 0, 0);
    __syncthreads();

    bf16x8 a[4], b[4];
#pragma unroll
    for (int m = 0; m < 4; ++m)
      a[m] = *reinterpret_cast<const bf16x8*>((const char*)As + aoff + m * 16 * 64);
#pragma unroll
    for (int n = 0; n < 4; ++n)
      b[n] = *reinterpret_cast<const bf16x8*>((const char*)Bs + boff + n * 16 * 64);
#pragma unroll
    for (int m = 0; m < 4; ++m)
#pragma unroll
      for (int n = 0; n < 4; ++n)
        acc[m][n] = __builtin_amdgcn_mfma_f32_16x16x32_bf16(a[m], b[n], acc[m][n], 0, 0, 0);
    __syncthreads();
  }

  // epilogue: bias (+Q scale) + scatter (t uniform per block)
  const int t = bn >> 3;   // 0:Q 1:K 2:V
  const float* bias = (t == 0) ? bq : (t == 1) ? bk : bv;
  unsigned short* dst = (t == 0) ? Qo : (t == 1) ? Ko : Vo;
  const float sc = (t == 0) ? 0.125f : 1.0f;   // 1/sqrt(64), exact scale
#pragma unroll
  for (int n = 0; n < 4; ++n) {
    const int gn = bn * 128 + wc * 64 + n * 16 + (lane & 15);
    const int d = gn & 1023;
    const int h = d >> 6, hd = d & 63;
    const float bias_v = bias[d];
#pragma unroll
    for (int m = 0; m < 4; ++m) {
      const int gm0 = bm * 128 + wr * 64 + m * 16 + ((lane >> 4) << 2);
      const int bb = gm0 >> 10;
      const int s0 = gm0 & 1023;
#pragma unroll
      for (int r = 0; r < 4; ++r) {
        const unsigned short val = f2bf((acc[m][n][r] + bias_v) * sc);
        if (t == 2) {
          // V transposed: [B][H][Hd][S]
          dst[(((size_t)bb * 16 + h) * 64 + hd) * 1024 + (size_t)(s0 + r)] = val;
        } else {
          dst[(((size_t)bb * 16 + h) * 1024 + (size_t)(s0 + r)) * 64 + hd] = val;
        }
      }
    }
  }
}

// ---------------------------------------------------------------------------
// Flash attention, swapped-operand 32x32x16.
// Block = (head, 128 q-rows), 4 waves x 32 q-rows. KV tiles of 64 rows.
// LDS: double-buffered {K[64][64] rows 128B, Vt[64][64]} staged linearly by
// global_load_lds with pre-swizzled global source; reads XOR-swizzle
// slot ^= (row&7) on 16B slots.  Lane owns q = lane&31; QK^T output rows give
// k = (reg&3)+8*(reg>>2)+4*(lane>>5) (+32 for s1).  P goes through a
// wave-private LDS tile [32 q][64 k] (u32 pair writes at absolute k addresses,
// XOR swizzle) and is read back as contiguous B-fragments for PV.
// ---------------------------------------------------------------------------
__global__ __launch_bounds__(256) void attn32(
    const unsigned short* __restrict__ Q, const unsigned short* __restrict__ K,
    const unsigned short* __restrict__ Vt, float* __restrict__ out) {
  __shared__ __align__(16) char smem[2][16384];
  __shared__ __align__(16) char psm[4][4096];   // per-wave P: [32 q][64 k] bf16

  const int tid = threadIdx.x;
  const int lane = tid & 63;
  const int ln31 = lane & 31;
  const int g = lane >> 5;
  const int w = tid >> 6;
  const int head = blockIdx.x & 127;   // b*16+h ; qt-major -> head pinned to XCD
  const int qt = blockIdx.x >> 7;

  const unsigned short* Qh = Q + (size_t)head * 65536;
  const unsigned short* Kh = K + (size_t)head * 65536;
  const unsigned short* Vh = Vt + (size_t)head * 65536;

  // Q fragments (B-operand, held all kernel): lane holds Q[q][dc*16 + g*8 + j]
  const int qrow = qt * 128 + w * 32 + ln31;
  bf16x8 qf[4];
#pragma unroll
  for (int dc = 0; dc < 4; ++dc)
    qf[dc] = *reinterpret_cast<const bf16x8*>(Qh + (size_t)qrow * 64 + dc * 16 + g * 8);

  // staging: 16KB/tile, 4x global_load_lds(16B)/thread; LDS linear,
  // global source pre-swizzled (slot ^ (row&7)).
  const int lbA = w * 1024 + lane * 16;        // [0, 4096)
  const int lbB = lbA + 4096;                  // [4096, 8192)
  const int rA = lbA >> 7, rB = lbB >> 7;
  const int cA = ((((lbA >> 4) & 7) ^ (rA & 7)) << 3);   // elements
  const int cB = ((((lbB >> 4) & 7) ^ (rB & 7)) << 3);
  const unsigned short* gK0 = Kh + rA * 64 + cA;     // + kt*4096
  const unsigned short* gK1 = Kh + rB * 64 + cB;
  const unsigned short* gV0 = Vh + rA * 1024 + cA;   // + kt*64
  const unsigned short* gV1 = Vh + rB * 1024 + cB;

  {
    char* b0 = smem[0] + w * 1024;
    __builtin_amdgcn_global_load_lds((gptr_t)gK0, (lptr_t)b0, 16, 0, 0);
    __builtin_amdgcn_global_load_lds((gptr_t)gK1, (lptr_t)(b0 + 4096), 16, 0, 0);
    __builtin_amdgcn_global_load_lds((gptr_t)gV0, (lptr_t)(b0 + 8192), 16, 0, 0);
    __builtin_amdgcn_global_load_lds((gptr_t)gV1, (lptr_t)(b0 + 12288), 16, 0, 0);
  }

  float m_ = -3e38f, l_ = 0.f;
  f32x16 acc0, acc1;
#pragma unroll
  for (int i = 0; i < 16; ++i) { acc0[i] = 0.f; acc1[i] = 0.f; }

  const int pswz = ln31 & 7;
  char* Pw = psm[w] + ln31 * 128 + 8 * g;   // + ((b ^ pswz)<<4) + 4*rp
  const char* Pr = psm[w] + ln31 * 128;     // + (((2t+g) ^ pswz)<<4)

  for (int kt = 0; kt < 16; ++kt) {
    __syncthreads();   // vmcnt(0)+lgkmcnt(0) drain: tile kt ready
    if (kt < 15) {     // prefetch tile kt+1 into the other buffer
      char* nb = smem[(kt + 1) & 1] + w * 1024;
      const int k1 = (kt + 1) * 4096, k2 = (kt + 1) * 64;
      __builtin_amdgcn_global_load_lds((gptr_t)(gK0 + k1), (lptr_t)nb, 16, 0, 0);
      __builtin_amdgcn_global_load_lds((gptr_t)(gK1 + k1), (lptr_t)(nb + 4096), 16, 0, 0);
      __builtin_amdgcn_global_load_lds((gptr_t)(gV0 + k2), (lptr_t)(nb + 8192), 16, 0, 0);
      __builtin_amdgcn_global_load_lds((gptr_t)(gV1 + k2), (lptr_t)(nb + 12288), 16, 0, 0);
    }
    const char* Kb_ = smem[kt & 1];
    const char* Vb_ = Kb_ + 8192;

    // S^T[k][q] = sum_d K[k][d] Q[q][d]  (2 kblk x 4 dchunk mfmas)
    f32x16 s0, s1;
#pragma unroll
    for (int i = 0; i < 16; ++i) { s0[i] = 0.f; s1[i] = 0.f; }
    const int r0 = ln31, r1 = 32 + ln31;
    const int sw0 = r0 & 7, sw1 = r1 & 7;
#pragma unroll
    for (int dc = 0; dc < 4; ++dc) {
      bf16x8 kf0 = *reinterpret_cast<const bf16x8*>(
          Kb_ + r0 * 128 + ((((dc << 1) | g) ^ sw0) << 4));
      bf16x8 kf1 = *reinterpret_cast<const bf16x8*>(
          Kb_ + r1 * 128 + ((((dc << 1) | g) ^ sw1) << 4));
      s0 = __builtin_amdgcn_mfma_f32_32x32x16_bf16(kf0, qf[dc], s0, 0, 0, 0);
      s1 = __builtin_amdgcn_mfma_f32_32x32x16_bf16(kf1, qf[dc], s1, 0, 0, 0);
    }

    // online softmax: q-row lane-local; partner lane^32 holds other half of k
    float tm = s0[0];
#pragma unroll
    for (int i = 1; i < 16; ++i) tm = fmaxf(tm, s0[i]);
#pragma unroll
    for (int i = 0; i < 16; ++i) tm = fmaxf(tm, s1[i]);
    tm = fmaxf(tm, __shfl_xor(tm, 32));
    const float mn = fmaxf(m_, tm);
    const float al = exp2f((m_ - mn) * LOG2E);
    m_ = mn;
    const float mnl = mn * LOG2E;
    float ts = 0.f;

    // P = exp(s-mn) -> bf16 (RNE), write pairs to wave-private LDS at
    // absolute k addresses: k = 8b + 4g + {0..3}; ts sums ROUNDED p.
#pragma unroll
    for (int b = 0; b < 4; ++b) {
      const float p0 = exp2f(fmaf(s0[4 * b + 0], LOG2E, -mnl));
      const float p1 = exp2f(fmaf(s0[4 * b + 1], LOG2E, -mnl));
      const float p2 = exp2f(fmaf(s0[4 * b + 2], LOG2E, -mnl));
      const float p3 = exp2f(fmaf(s0[4 * b + 3], LOG2E, -mnl));
      const unsigned short h0 = f2bf(p0), h1 = f2bf(p1), h2 = f2bf(p2), h3 = f2bf(p3);
      ts += bf2f(h0) + bf2f(h1) + bf2f(h2) + bf2f(h3);
      char* pb = Pw + ((b ^ pswz) << 4);
      *(unsigned int*)(pb)     = (unsigned int)h0 | ((unsigned int)h1 << 16);
      *(unsigned int*)(pb + 4) = (unsigned int)h2 | ((unsigned int)h3 << 16);
    }
#pragma unroll
    for (int b = 4; b < 8; ++b) {
      const float p0 = exp2f(fmaf(s1[4 * (b - 4) + 0], LOG2E, -mnl));
      const float p1 = exp2f(fmaf(s1[4 * (b - 4) + 1], LOG2E, -mnl));
      const float p2 = exp2f(fmaf(s1[4 * (b - 4) + 2], LOG2E, -mnl));
      const float p3 = exp2f(fmaf(s1[4 * (b - 4) + 3], LOG2E, -mnl));
      const unsigned short h0 = f2bf(p0), h1 = f2bf(p1), h2 = f2bf(p2), h3 = f2bf(p3);
      ts += bf2f(h0) + bf2f(h1) + bf2f(h2) + bf2f(h3);
      char* pb = Pw + ((b ^ pswz) << 4);
      *(unsigned int*)(pb)     = (unsigned int)h0 | ((unsigned int)h1 << 16);
      *(unsigned int*)(pb + 4) = (unsigned int)h2 | ((unsigned int)h3 << 16);
    }
    ts += __shfl_xor(ts, 32);
    l_ = l_ * al + ts;
#pragma unroll
    for (int i = 0; i < 16; ++i) { acc0[i] *= al; acc1[i] *= al; }

    // P B-fragments: lane reads row q=ln31, k = 16t + 8g + {0..7}
    bf16x8 pfv[4];
#pragma unroll
    for (int t = 0; t < 4; ++t)
      pfv[t] = *reinterpret_cast<const bf16x8*>(Pr + ((((t << 1) | g) ^ pswz) << 4));

    // ctx^T[d][q] += sum_k V^T[d][k] P^T[k][q]   (2 dblk x 4 t mfmas)
#pragma unroll
    for (int t = 0; t < 4; ++t) {
      bf16x8 vf0 = *reinterpret_cast<const bf16x8*>(
          Vb_ + r0 * 128 + ((((t << 1) | g) ^ sw0) << 4));
      bf16x8 vf1 = *reinterpret_cast<const bf16x8*>(
          Vb_ + r1 * 128 + ((((t << 1) | g) ^ sw1) << 4));
      acc0 = __builtin_amdgcn_mfma_f32_32x32x16_bf16(vf0, pfv[t], acc0, 0, 0, 0);
      acc1 = __builtin_amdgcn_mfma_f32_32x32x16_bf16(vf1, pfv[t], acc1, 0, 0, 0);
    }
  }

  // epilogue: out[b][q][h*64 + d], d = (reg&3) + 8*(reg>>2) + 4g + 32*dblk
  const float invl = 1.0f / l_;
  const int bb = head >> 4, hh = head & 15;
  float* orow = out + ((size_t)bb * 1024 + qrow) * 1024 + hh * 64;
#pragma unroll
  for (int rq = 0; rq < 4; ++rq) {
    const int d0 = rq * 8 + g * 4;
    float4 v0, v1;
    v0.x = acc0[rq * 4 + 0] * invl; v0.y = acc0[rq * 4 + 1] * invl;
    v0.z = acc0[rq * 4 + 2] * invl; v0.w = acc0[rq * 4 + 3] * invl;
    v1.x = acc1[rq * 4 + 0] * invl; v1.y = acc1[rq * 4 + 1] * invl;
    v1.z = acc1[rq * 4 + 2] * invl; v1.w = acc1[rq * 4 + 3] * invl;
    *reinterpret_cast<float4*>(orow + d0) = v0;
    *reinterpret_cast<float4*>(orow + 32 + d0) = v1;
  }
}

// ---------------------------------------------------------------------------
extern "C" void kernel_launch(void* const* d_in, const int* in_sizes, int n_in,
                              void* d_out, int out_size, void* d_ws, size_t ws_size,
                              hipStream_t stream) {
  const float* x  = (const float*)d_in[0];
  const float* Wq = (const float*)d_in[1];
  const float* Wk = (const float*)d_in[2];
  const float* Wv = (const float*)d_in[3];
  const float* bq = (const float*)d_in[4];
  const float* bk = (const float*)d_in[5];
  const float* bv = (const float*)d_in[6];
  float* out = (float*)d_out;

  char* ws = (char*)d_ws;
  unsigned short* Xb = (unsigned short*)(ws);                               // 16 MB
  unsigned short* Wb = (unsigned short*)(ws + (size_t)16 * 1024 * 1024);    //  6 MB
  unsigned short* Qb = (unsigned short*)(ws + (size_t)22 * 1024 * 1024);    // 16 MB
  unsigned short* Kb = Qb + (size_t)8 * 1024 * 1024;                        // 16 MB
  unsigned short* Vb = Kb + (size_t)8 * 1024 * 1024;                        // 16 MB (transposed)

  // fp32 -> bf16
  cvt_f32_bf16<<<8192, 256, 0, stream>>>(x, Xb, 2097152);
  cvt_f32_bf16<<<1024, 256, 0, stream>>>(Wq, Wb, 262144);
  cvt_f32_bf16<<<1024, 256, 0, stream>>>(Wk, Wb + 1048576, 262144);
  cvt_f32_bf16<<<1024, 256, 0, stream>>>(Wv, Wb + 2097152, 262144);

  // fused QKV projection (M=8192, N=3072, K=1024); Q pre-scaled, V transposed
  qkv_gemm<<<1536, 256, 0, stream>>>(Xb, Wb, bq, bk, bv, Qb, Kb, Vb);

  // flash attention: 8 q-tiles(128 rows) x 128 heads
  attn32<<<1024, 256, 0, stream>>>(Qb, Kb, Vb, out);
}

// Round 5
// 160.968 us; speedup vs baseline: 1.5356x; 1.2061x over previous
//
#include <hip/hip_runtime.h>
#include <hip/hip_bf16.h>
#include <cstdint>
#include <cstddef>

// ---------------------------------------------------------------------------
// Fused MHA forward: out = softmax((xWq^T+bq)(xWk^T+bk)^T / sqrt(Hd)) (xWv^T+bv)
// B=8, S=1024, D=1024, H=16, Hd=64.  bf16 MFMA pipeline, fp32 accum/output.
// Round 5 = round 4 with the __hip_bfloat162 bit_cast fixed via memcpy:
// (1) V transposed by a dedicated LDS kernel; (2) attn VALU diet: compiler
// bf16 cvt, defer-max (T13), b64 P writes, hoisted LDS offsets,
// launch_bounds(256,3), setprio (T5).
// ---------------------------------------------------------------------------

typedef __attribute__((ext_vector_type(8))) short bf16x8;
typedef __attribute__((ext_vector_type(8))) unsigned short u16x8;
typedef __attribute__((ext_vector_type(4))) float f32x4;
typedef __attribute__((ext_vector_type(16))) float f32x16;

typedef const __attribute__((address_space(1))) void* gptr_t;
typedef __attribute__((address_space(3))) void* lptr_t;

#define LOG2E 1.44269504088896340736f

__device__ __forceinline__ unsigned short f2bf(float f) {
  unsigned int u = __float_as_uint(f);
  u += 0x7fffu + ((u >> 16) & 1u);       // round-to-nearest-even
  return (unsigned short)(u >> 16);
}

__device__ __forceinline__ unsigned int pack_bf16x2(float lo, float hi) {
  const __hip_bfloat162 h = __float22bfloat162_rn(float2{lo, hi});
  unsigned int u;
  __builtin_memcpy(&u, &h, 4);
  return u;
}

__device__ __forceinline__ float vmax16(const f32x16& v) {
  float a = fmaxf(fmaxf(v[0], v[1]), fmaxf(v[2], v[3]));
  float b = fmaxf(fmaxf(v[4], v[5]), fmaxf(v[6], v[7]));
  float c = fmaxf(fmaxf(v[8], v[9]), fmaxf(v[10], v[11]));
  float d = fmaxf(fmaxf(v[12], v[13]), fmaxf(v[14], v[15]));
  return fmaxf(fmaxf(a, b), fmaxf(c, d));
}

// ---------------------------------------------------------------------------
// fp32 -> bf16 conversion, 4 elems/thread
// ---------------------------------------------------------------------------
__global__ void cvt_f32_bf16(const float* __restrict__ src,
                             unsigned short* __restrict__ dst, int n4) {
  int i = blockIdx.x * blockDim.x + threadIdx.x;
  if (i >= n4) return;
  float4 v = reinterpret_cast<const float4*>(src)[i];
  ushort4 o;
  o.x = f2bf(v.x); o.y = f2bf(v.y); o.z = f2bf(v.z); o.w = f2bf(v.w);
  reinterpret_cast<ushort4*>(dst)[i] = o;
}

// 3 weight matrices in one launch: blocks [0,1024) Wq, [1024,2048) Wk, rest Wv
__global__ void cvt_w3(const float* __restrict__ wq, const float* __restrict__ wk,
                       const float* __restrict__ wv, unsigned short* __restrict__ dst) {
  const int b = blockIdx.x;          // 0..3071
  const int sel = b >> 10;
  const float* src = (sel == 0) ? wq : (sel == 1) ? wk : wv;
  const int i = (b & 1023) * 256 + threadIdx.x;
  float4 v = reinterpret_cast<const float4*>(src)[i];
  ushort4 o;
  o.x = f2bf(v.x); o.y = f2bf(v.y); o.z = f2bf(v.z); o.w = f2bf(v.w);
  reinterpret_cast<ushort4*>(dst + (size_t)sel * 1048576)[i] = o;
}

// ---------------------------------------------------------------------------
// QKV GEMM: Y[8192][3072] = Xb[8192][1024] @ Wb[3072][1024]^T  (+bias)
// 128x128 tile, BK=32, 4 waves (2x2), 16x16x32 bf16 MFMA, global_load_lds.
// Epilogue: Q scaled by 0.125 (exact); Q/K/V all -> [B][H][S][Hd] bf16.
// ---------------------------------------------------------------------------
__global__ __launch_bounds__(256) void qkv_gemm(
    const unsigned short* __restrict__ Xb, const unsigned short* __restrict__ Wb,
    const float* __restrict__ bq, const float* __restrict__ bk,
    const float* __restrict__ bv,
    unsigned short* __restrict__ Qo, unsigned short* __restrict__ Ko,
    unsigned short* __restrict__ Vo) {
  __shared__ unsigned short As[128 * 32];   // [row][k] 64B rows
  __shared__ unsigned short Bs[128 * 32];

  const int tid = threadIdx.x;
  const int lane = tid & 63;
  const int w = tid >> 6;
  const int wr = w >> 1, wc = w & 1;
  const int bm = blockIdx.x & 63;   // 64 M-blocks
  const int bn = blockIdx.x >> 6;   // 24 N-blocks

  const f32x4 vzero = {0.f, 0.f, 0.f, 0.f};
  f32x4 acc[4][4];
#pragma unroll
  for (int m = 0; m < 4; ++m)
#pragma unroll
    for (int n = 0; n < 4; ++n) acc[m][n] = vzero;

  // staging: per wave 2 chunks of 1KB per matrix; chunk = 16 rows x 64B
  const int c0 = w * 2, c1 = w * 2 + 1;
  const int srow0 = c0 * 16 + (lane >> 2);
  const int srow1 = c1 * 16 + (lane >> 2);
  const int scol = (lane & 3) * 8;
  const unsigned short* gA0 = Xb + (size_t)(bm * 128 + srow0) * 1024 + scol;
  const unsigned short* gA1 = Xb + (size_t)(bm * 128 + srow1) * 1024 + scol;
  const unsigned short* gB0 = Wb + (size_t)(bn * 128 + srow0) * 1024 + scol;
  const unsigned short* gB1 = Wb + (size_t)(bn * 128 + srow1) * 1024 + scol;
  char* lA0 = (char*)As + c0 * 1024;
  char* lA1 = (char*)As + c1 * 1024;
  char* lB0 = (char*)Bs + c0 * 1024;
  char* lB1 = (char*)Bs + c1 * 1024;

  const int aoff = (wr * 64 + (lane & 15)) * 64 + (lane >> 4) * 16;
  const int boff = (wc * 64 + (lane & 15)) * 64 + (lane >> 4) * 16;

  for (int kt = 0; kt < 32; ++kt) {
    const int k0 = kt * 32;
    __builtin_amdgcn_global_load_lds((gptr_t)(gA0 + k0), (lptr_t)lA0, 16, 0, 0);
    __builtin_amdgcn_global_load_lds((gptr_t)(gA1 + k0), (lptr_t)lA1, 16, 0, 0);
    __builtin_amdgcn_global_load_lds((gptr_t)(gB0 + k0), (lptr_t)lB0, 16, 0, 0);
    __builtin_amdgcn_global_load_lds((gptr_t)(gB1 + k0), (lptr_t)lB1, 16, 0, 0);
    __syncthreads();

    bf16x8 a[4], b[4];
#pragma unroll
    for (int m = 0; m < 4; ++m)
      a[m] = *reinterpret_cast<const bf16x8*>((const char*)As + aoff + m * 16 * 64);
#pragma unroll
    for (int n = 0; n < 4; ++n)
      b[n] = *reinterpret_cast<const bf16x8*>((const char*)Bs + boff + n * 16 * 64);
#pragma unroll
    for (int m = 0; m < 4; ++m)
#pragma unroll
      for (int n = 0; n < 4; ++n)
        acc[m][n] = __builtin_amdgcn_mfma_f32_16x16x32_bf16(a[m], b[n], acc[m][n], 0, 0, 0);
    __syncthreads();
  }

  // epilogue: bias (+Q scale) + scatter (t uniform per block)
  const int t = bn >> 3;   // 0:Q 1:K 2:V
  const float* bias = (t == 0) ? bq : (t == 1) ? bk : bv;
  unsigned short* dst = (t == 0) ? Qo : (t == 1) ? Ko : Vo;
  const float sc = (t == 0) ? 0.125f : 1.0f;   // 1/sqrt(64), exact scale
#pragma unroll
  for (int n = 0; n < 4; ++n) {
    const int gn = bn * 128 + wc * 64 + n * 16 + (lane & 15);
    const int d = gn & 1023;
    const int h = d >> 6, hd = d & 63;
    const float bias_v = bias[d];
#pragma unroll
    for (int m = 0; m < 4; ++m) {
      const int gm0 = bm * 128 + wr * 64 + m * 16 + ((lane >> 4) << 2);
      const int bb = gm0 >> 10;
      const int s0 = gm0 & 1023;
#pragma unroll
      for (int r = 0; r < 4; ++r) {
        dst[(((size_t)bb * 16 + h) * 1024 + (size_t)(s0 + r)) * 64 + hd] =
            f2bf((acc[m][n][r] + bias_v) * sc);
      }
    }
  }
}

// ---------------------------------------------------------------------------
// V transpose: [128 heads][1024 s][64 d] -> [128 heads][64 d][1024 s]
// 64x64 tiles through LDS with XOR column swizzle.
// ---------------------------------------------------------------------------
__global__ __launch_bounds__(256) void transpose_v(
    const unsigned short* __restrict__ Vn, unsigned short* __restrict__ Vt) {
  __shared__ __align__(16) unsigned short T[64][72];   // 144B rows
  const int tid = threadIdx.x;
  const int head = blockIdx.x & 127;
  const int st = blockIdx.x >> 7;
  const unsigned short* src = Vn + (size_t)head * 65536 + (size_t)st * 64 * 64;
  unsigned short* dst = Vt + (size_t)head * 65536 + (size_t)st * 64;
#pragma unroll
  for (int i = 0; i < 2; ++i) {
    const int idx = tid + i * 256;           // 0..511
    const int r = idx >> 3, ch = idx & 7;
    u16x8 v = *reinterpret_cast<const u16x8*>(src + r * 64 + ch * 8);
#pragma unroll
    for (int j = 0; j < 8; ++j)
      T[ch * 8 + j][r ^ (ch << 3)] = (unsigned short)v[j];
  }
  __syncthreads();
#pragma unroll
  for (int i = 0; i < 2; ++i) {
    const int idx = tid + i * 256;
    const int d = idx >> 3, ch = idx & 7;
    u16x8 v = *reinterpret_cast<const u16x8*>(&T[d][(ch ^ (d >> 3)) << 3]);
    *reinterpret_cast<u16x8*>(dst + (size_t)d * 1024 + ch * 8) = v;
  }
}

// ---------------------------------------------------------------------------
// Flash attention, swapped-operand 32x32x16 (structure verified round 3).
// Block = (head, 128 q-rows), 4 waves x 32 q-rows. KV tiles of 64 rows.
// VALU diet: compiler bf16 cvt pairs, defer-max THR=5, b64 P writes,
// hoisted shared XOR offsets (sw0==sw1==pswz), setprio around MFMA.
// ---------------------------------------------------------------------------
__global__ __launch_bounds__(256, 3) void attn32(
    const unsigned short* __restrict__ Q, const unsigned short* __restrict__ K,
    const unsigned short* __restrict__ Vt, float* __restrict__ out) {
  __shared__ __align__(16) char smem[2][16384];
  __shared__ __align__(16) char psm[4][4096];   // per-wave P: [32 q][64 k] bf16

  const int tid = threadIdx.x;
  const int lane = tid & 63;
  const int ln31 = lane & 31;
  const int g = lane >> 5;
  const int w = tid >> 6;
  const int head = blockIdx.x & 127;   // b*16+h ; qt-major -> head pinned to XCD
  const int qt = blockIdx.x >> 7;

  const unsigned short* Qh = Q + (size_t)head * 65536;
  const unsigned short* Kh = K + (size_t)head * 65536;
  const unsigned short* Vh = Vt + (size_t)head * 65536;

  // Q fragments (B-operand, held all kernel): lane holds Q[q][dc*16 + g*8 + j]
  const int qrow = qt * 128 + w * 32 + ln31;
  bf16x8 qf[4];
#pragma unroll
  for (int dc = 0; dc < 4; ++dc)
    qf[dc] = *reinterpret_cast<const bf16x8*>(Qh + (size_t)qrow * 64 + dc * 16 + g * 8);

  // staging: 16KB/tile, 4x global_load_lds(16B)/thread; LDS linear,
  // global source pre-swizzled (slot ^ (row&7)).
  const int lbA = w * 1024 + lane * 16;        // [0, 4096)
  const int lbB = lbA + 4096;                  // [4096, 8192)
  const int rA = lbA >> 7, rB = lbB >> 7;
  const int cA = ((((lbA >> 4) & 7) ^ (rA & 7)) << 3);   // elements
  const int cB = ((((lbB >> 4) & 7) ^ (rB & 7)) << 3);
  const unsigned short* gK0 = Kh + rA * 64 + cA;     // + kt*4096
  const unsigned short* gK1 = Kh + rB * 64 + cB;
  const unsigned short* gV0 = Vh + rA * 1024 + cA;   // + kt*64
  const unsigned short* gV1 = Vh + rB * 1024 + cB;

  {
    char* b0 = smem[0] + w * 1024;
    __builtin_amdgcn_global_load_lds((gptr_t)gK0, (lptr_t)b0, 16, 0, 0);
    __builtin_amdgcn_global_load_lds((gptr_t)gK1, (lptr_t)(b0 + 4096), 16, 0, 0);
    __builtin_amdgcn_global_load_lds((gptr_t)gV0, (lptr_t)(b0 + 8192), 16, 0, 0);
    __builtin_amdgcn_global_load_lds((gptr_t)gV1, (lptr_t)(b0 + 12288), 16, 0, 0);
  }

  float m_ = -3e38f, l_ = 0.f;
  f32x16 acc0, acc1;
#pragma unroll
  for (int i = 0; i < 16; ++i) { acc0[i] = 0.f; acc1[i] = 0.f; }

  // shared XOR swizzle: rows r0=ln31 and r1=32+ln31 have (row&7) == ln31&7
  const int swz = (ln31 & 7) << 4;
  const int rowb0 = ln31 * 128;              // byte row offset in 64x64 tile
  int boff[4];                               // slot offsets (QK^T dc / PV t / P read)
#pragma unroll
  for (int dc = 0; dc < 4; ++dc) boff[dc] = ((((dc << 1) | g) << 4) ^ swz);
  int woff[8];                               // P write slots
#pragma unroll
  for (int b = 0; b < 8; ++b) woff[b] = ((b << 4) ^ swz);
  char* Pw0 = psm[w] + ln31 * 128 + 8 * g;
  const char* Pr0 = psm[w] + ln31 * 128;

  for (int kt = 0; kt < 16; ++kt) {
    __syncthreads();   // vmcnt(0)+lgkmcnt(0) drain: tile kt ready
    if (kt < 15) {     // prefetch tile kt+1 into the other buffer
      char* nb = smem[(kt + 1) & 1] + w * 1024;
      const int k1 = (kt + 1) * 4096, k2 = (kt + 1) * 64;
      __builtin_amdgcn_global_load_lds((gptr_t)(gK0 + k1), (lptr_t)nb, 16, 0, 0);
      __builtin_amdgcn_global_load_lds((gptr_t)(gK1 + k1), (lptr_t)(nb + 4096), 16, 0, 0);
      __builtin_amdgcn_global_load_lds((gptr_t)(gV0 + k2), (lptr_t)(nb + 8192), 16, 0, 0);
      __builtin_amdgcn_global_load_lds((gptr_t)(gV1 + k2), (lptr_t)(nb + 12288), 16, 0, 0);
    }
    const char* Kb_ = smem[kt & 1] + rowb0;
    const char* Vb_ = Kb_ + 8192;

    // S^T[k][q] = sum_d K[k][d] Q[q][d]  (2 kblk x 4 dchunk mfmas)
    f32x16 s0, s1;
#pragma unroll
    for (int i = 0; i < 16; ++i) { s0[i] = 0.f; s1[i] = 0.f; }
    __builtin_amdgcn_s_setprio(1);
#pragma unroll
    for (int dc = 0; dc < 4; ++dc) {
      bf16x8 kf0 = *reinterpret_cast<const bf16x8*>(Kb_ + boff[dc]);
      bf16x8 kf1 = *reinterpret_cast<const bf16x8*>(Kb_ + 4096 + boff[dc]);
      s0 = __builtin_amdgcn_mfma_f32_32x32x16_bf16(kf0, qf[dc], s0, 0, 0, 0);
      s1 = __builtin_amdgcn_mfma_f32_32x32x16_bf16(kf1, qf[dc], s1, 0, 0, 0);
    }
    __builtin_amdgcn_s_setprio(0);

    // ---- online softmax with defer-max (T13, THR=5) ----
    float tm = fmaxf(vmax16(s0), vmax16(s1));
    tm = fmaxf(tm, __shfl_xor(tm, 32));
    if (__any(tm > m_ + 5.0f)) {
      const float mn = fmaxf(m_, tm);
      const float al = exp2f((m_ - mn) * LOG2E);
      m_ = mn;
      l_ *= al;
#pragma unroll
      for (int i = 0; i < 16; ++i) { acc0[i] *= al; acc1[i] *= al; }
    }
    const float mnl = m_ * LOG2E;
    float ts = 0.f;

    // P = exp(s-m_) -> bf16 pairs (compiler cvt), b64 writes to wave-private
    // LDS at absolute k addresses: k = 8b + 4g + {0..3}
#pragma unroll
    for (int b = 0; b < 4; ++b) {
      const float p0 = exp2f(fmaf(s0[4 * b + 0], LOG2E, -mnl));
      const float p1 = exp2f(fmaf(s0[4 * b + 1], LOG2E, -mnl));
      const float p2 = exp2f(fmaf(s0[4 * b + 2], LOG2E, -mnl));
      const float p3 = exp2f(fmaf(s0[4 * b + 3], LOG2E, -mnl));
      ts += (p0 + p1) + (p2 + p3);
      const unsigned long long wp =
          (unsigned long long)pack_bf16x2(p0, p1) |
          ((unsigned long long)pack_bf16x2(p2, p3) << 32);
      *(unsigned long long*)(Pw0 + woff[b]) = wp;
    }
#pragma unroll
    for (int b = 4; b < 8; ++b) {
      const float p0 = exp2f(fmaf(s1[4 * (b - 4) + 0], LOG2E, -mnl));
      const float p1 = exp2f(fmaf(s1[4 * (b - 4) + 1], LOG2E, -mnl));
      const float p2 = exp2f(fmaf(s1[4 * (b - 4) + 2], LOG2E, -mnl));
      const float p3 = exp2f(fmaf(s1[4 * (b - 4) + 3], LOG2E, -mnl));
      ts += (p0 + p1) + (p2 + p3);
      const unsigned long long wp =
          (unsigned long long)pack_bf16x2(p0, p1) |
          ((unsigned long long)pack_bf16x2(p2, p3) << 32);
      *(unsigned long long*)(Pw0 + woff[b]) = wp;
    }
    ts += __shfl_xor(ts, 32);
    l_ += ts;

    // P B-fragments: lane reads row q=ln31, k = 16t + 8g + {0..7}
    bf16x8 pfv[4];
#pragma unroll
    for (int t = 0; t < 4; ++t)
      pfv[t] = *reinterpret_cast<const bf16x8*>(Pr0 + boff[t]);

    // ctx^T[d][q] += sum_k V^T[d][k] P^T[k][q]   (2 dblk x 4 t mfmas)
    __builtin_amdgcn_s_setprio(1);
#pragma unroll
    for (int t = 0; t < 4; ++t) {
      bf16x8 vf0 = *reinterpret_cast<const bf16x8*>(Vb_ + boff[t]);
      bf16x8 vf1 = *reinterpret_cast<const bf16x8*>(Vb_ + 4096 + boff[t]);
      acc0 = __builtin_amdgcn_mfma_f32_32x32x16_bf16(vf0, pfv[t], acc0, 0, 0, 0);
      acc1 = __builtin_amdgcn_mfma_f32_32x32x16_bf16(vf1, pfv[t], acc1, 0, 0, 0);
    }
    __builtin_amdgcn_s_setprio(0);
  }

  // epilogue: out[b][q][h*64 + d], d = (reg&3) + 8*(reg>>2) + 4g + 32*dblk
  const float invl = 1.0f / l_;
  const int bb = head >> 4, hh = head & 15;
  float* orow = out + ((size_t)bb * 1024 + qrow) * 1024 + hh * 64;
#pragma unroll
  for (int rq = 0; rq < 4; ++rq) {
    const int d0 = rq * 8 + g * 4;
    float4 v0, v1;
    v0.x = acc0[rq * 4 + 0] * invl; v0.y = acc0[rq * 4 + 1] * invl;
    v0.z = acc0[rq * 4 + 2] * invl; v0.w = acc0[rq * 4 + 3] * invl;
    v1.x = acc1[rq * 4 + 0] * invl; v1.y = acc1[rq * 4 + 1] * invl;
    v1.z = acc1[rq * 4 + 2] * invl; v1.w = acc1[rq * 4 + 3] * invl;
    *reinterpret_cast<float4*>(orow + d0) = v0;
    *reinterpret_cast<float4*>(orow + 32 + d0) = v1;
  }
}

// ---------------------------------------------------------------------------
extern "C" void kernel_launch(void* const* d_in, const int* in_sizes, int n_in,
                              void* d_out, int out_size, void* d_ws, size_t ws_size,
                              hipStream_t stream) {
  const float* x  = (const float*)d_in[0];
  const float* Wq = (const float*)d_in[1];
  const float* Wk = (const float*)d_in[2];
  const float* Wv = (const float*)d_in[3];
  const float* bq = (const float*)d_in[4];
  const float* bk = (const float*)d_in[5];
  const float* bv = (const float*)d_in[6];
  float* out = (float*)d_out;

  char* ws = (char*)d_ws;
  unsigned short* Xb = (unsigned short*)(ws);                               // 16 MB; reused as Vt
  unsigned short* Wb = (unsigned short*)(ws + (size_t)16 * 1024 * 1024);    //  6 MB
  unsigned short* Qb = (unsigned short*)(ws + (size_t)22 * 1024 * 1024);    // 16 MB
  unsigned short* Kb = Qb + (size_t)8 * 1024 * 1024;                        // 16 MB
  unsigned short* Vb = Kb + (size_t)8 * 1024 * 1024;                        // 16 MB (natural V)
  unsigned short* Vt = Xb;   // Xb is dead after the GEMM; reuse for V^T

  // fp32 -> bf16
  cvt_f32_bf16<<<8192, 256, 0, stream>>>(x, Xb, 2097152);
  cvt_w3<<<3072, 256, 0, stream>>>(Wq, Wk, Wv, Wb);

  // fused QKV projection (M=8192, N=3072, K=1024); Q pre-scaled
  qkv_gemm<<<1536, 256, 0, stream>>>(Xb, Wb, bq, bk, bv, Qb, Kb, Vb);

  // V: [B,H,S,Hd] -> [B,H,Hd,S]
  transpose_v<<<2048, 256, 0, stream>>>(Vb, Vt);

  // flash attention: 8 q-tiles(128 rows) x 128 heads
  attn32<<<1024, 256, 0, stream>>>(Qb, Kb, Vt, out);
}